// Round 4
// baseline (115.038 us; speedup 1.0000x reference)
//
#include <hip/hip_runtime.h>
#include <math.h>

#define BATCH 64
#define H 512
#define W 512
#define KRAD 15
#define STRIP 32               // output rows per block
#define NSTRIP (H / STRIP)     // 16 strips per image
#define RING 40                // LDS ring slots (bf16 hsum rows); live range = 39

__device__ __forceinline__ float wave_reduce(float v) {
    #pragma unroll
    for (int off = 32; off > 0; off >>= 1) v += __shfl_xor(v, off);
    return v;
}

// barrier that waits only LDS ops (keeps global loads in flight across it)
__device__ __forceinline__ void lds_barrier() {
    asm volatile("s_waitcnt lgkmcnt(0)" ::: "memory");
    __builtin_amdgcn_s_barrier();
    asm volatile("" ::: "memory");
}

// f32 -> bf16 bits (round-to-nearest-even)
__device__ __forceinline__ unsigned bf16b(float f) {
    unsigned u = __float_as_uint(f);
    return (u + 0x7FFFu + ((u >> 16) & 1u)) >> 16;
}
__device__ __forceinline__ float fbf16(unsigned short s) {
    return __uint_as_float(((unsigned)s) << 16);
}

__device__ __forceinline__ void load_row(const float* __restrict__ base, int r, int lane,
                                         float4& a, float4& b) {
    if (0 <= r && r < H) {
        const float4* p4 = reinterpret_cast<const float4*>(base + (size_t)r * W + lane * 8);
        a = p4[0]; b = p4[1];
    } else {
        a = make_float4(0.f, 0.f, 0.f, 0.f);
        b = a;
    }
}

// Wave-wide horizontal 31-box-sum of one row (from registers), bf16-pack to LDS.
__device__ __forceinline__ void scan_store(float4 va, float4 vb, int lane,
                                           unsigned short* dst) {
    float v[8] = {va.x, va.y, va.z, va.w, vb.x, vb.y, vb.z, vb.w};
    float P[8];
    float run = 0.f;
    #pragma unroll
    for (int k = 0; k < 8; ++k) { run += v[k]; P[k] = run; }
    float scan = run;
    #pragma unroll
    for (int off = 1; off < 64; off <<= 1) {
        float n = __shfl_up(scan, off);
        if (lane >= off) scan += n;
    }
    const float excl = scan - run;
    #pragma unroll
    for (int k = 0; k < 8; ++k) P[k] += excl;        // inclusive prefix at x=8*lane+k
    const float total = __shfl(P[7], 63);
    // out[x] = P[min(x+15,511)] - (x>=16 ? P[x-16] : 0)
    float shA[8], shB[8];
    shA[0] = __shfl_down(P[7], 1);
    #pragma unroll
    for (int k = 1; k < 8; ++k) shA[k] = __shfl_down(P[k - 1], 2);
    #pragma unroll
    for (int k = 0; k < 8; ++k) shB[k] = __shfl_up(P[k], 2);
    const int xb = lane * 8;
    float o[8];
    #pragma unroll
    for (int k = 0; k < 8; ++k) {
        const int x = xb + k;
        const float A  = (x + KRAD <= W - 1) ? shA[k] : total;
        const float Bv = (x >= KRAD + 1) ? shB[k] : 0.f;
        o[k] = A - Bv;
    }
    uint4 wv;
    wv.x = bf16b(o[0]) | (bf16b(o[1]) << 16);
    wv.y = bf16b(o[2]) | (bf16b(o[3]) << 16);
    wv.z = bf16b(o[4]) | (bf16b(o[5]) << 16);
    wv.w = bf16b(o[6]) | (bf16b(o[7]) << 16);
    *reinterpret_cast<uint4*>(dst + xb) = wv;        // 16B, conflict-free
}

// -------- Fused: horizontal scan -> 40-slot bf16 LDS ring -> vertical window + loss.
// slot(row) = (row - r0 + 16) mod 40; all indices compile-time via full unroll.
__global__ __launch_bounds__(512, 8) void fused_kernel(const float* __restrict__ pred,
                                                       const float* __restrict__ mask,
                                                       float2* __restrict__ partials) {
    __shared__ unsigned short ring[RING][W];         // 40960 B exactly

    const int tid  = threadIdx.x;
    const int wave = tid >> 6;
    const int lane = tid & 63;
    const int img   = blockIdx.x >> 4;               // NSTRIP = 16
    const int strip = blockIdx.x & 15;
    const int r0 = strip * STRIP;
    const int c  = tid;
    const float* mk = mask + (size_t)img * (H * W);
    const float* pr = pred + (size_t)img * (H * W);

    // Prologue: fill offsets 0..30 (rows r0-16 .. r0+14), pipelined 1-deep.
    {
        float4 pa, pb;
        int pidx = wave;
        load_row(mk, r0 - 16 + pidx, lane, pa, pb);
        #pragma unroll
        for (int gp = 0; gp < 4; ++gp) {
            float4 na, nb;
            const int nidx = pidx + 8;
            if (gp < 3 && nidx < 31) load_row(mk, r0 - 16 + nidx, lane, na, nb);
            if (pidx < 31) scan_store(pa, pb, lane, &ring[pidx][0]);
            pa = na; pb = nb; pidx = nidx;
        }
    }

    // Preload scan input for group 0 (rows r0+15+wave)
    float4 sva, svb;
    load_row(mk, r0 + 15 + wave, lane, sva, svb);

    lds_barrier();

    // Initial vertical sum: offsets 1..30 (rows r0-15 .. r0+14)
    float vsum = 0.f;
    #pragma unroll
    for (int s = 1; s <= 30; ++s) vsum += fbf16(ring[s][c]);

    float s0 = 0.f, s1 = 0.f;
    const float inv_k2 = 1.0f / 961.0f;

    #pragma unroll
    for (int g = 0; g < STRIP / 8; ++g) {
        // Phase A: store scan of row r0+8g+15+wave at offset 8g+31+wave
        {
            const int off = 8 * g + 31 + wave;
            const int slot = (off >= RING) ? off - RING : off;
            scan_store(sva, svb, lane, &ring[slot][0]);
        }
        // Prefetch next group's scan input; stays in flight across lds_barrier
        if (g + 1 < STRIP / 8) load_row(mk, r0 + 8 * (g + 1) + 15 + wave, lane, sva, svb);

        lds_barrier();

        // Phase B: batch LDS + global reads for 8 rows, then register chain
        float addv[8], subv[8], m[8], p[8];
        #pragma unroll
        for (int i = 0; i < 8; ++i) {
            const int offA = 8 * g + 31 + i;                 // compile-time
            const int slotA = (offA >= RING) ? offA - RING : offA;
            addv[i] = fbf16(ring[slotA][c]);
            subv[i] = fbf16(ring[8 * g + i][c]);             // never wraps
        }
        #pragma unroll
        for (int i = 0; i < 8; ++i) {
            const int y = r0 + 8 * g + i;
            m[i] = mk[(size_t)y * W + c];
            p[i] = pr[(size_t)y * W + c];
        }
        #pragma unroll
        for (int i = 0; i < 8; ++i) {
            vsum += addv[i] - subv[i];                       // window [y-15, y+15]
            const float avg = vsum * inv_k2;
            const float w = 1.0f + 5.0f * fabsf(avg - m[i]);
            const float e = __expf(-fabsf(p[i]));
            const float softplus = __logf(1.0f + e);         // log1p(e), e in (0,1]
            const float bce = fmaxf(p[i], 0.0f) - p[i] * m[i] + softplus;
            const float r1pe = __builtin_amdgcn_rcpf(1.0f + e);
            const float sig = (p[i] >= 0.0f) ? r1pe : e * r1pe;
            const float inter = sig * m[i];
            const float denom = sig + m[i] - inter + 1.0f;   // union - inter + 1
            const float iou = 1.0f - (inter + 1.0f) * __builtin_amdgcn_rcpf(denom);
            s0 += w;
            s1 += w * (bce + iou);
        }
        lds_barrier();   // ring slots free to overwrite next group
    }

    s0 = wave_reduce(s0);
    s1 = wave_reduce(s1);
    float2* wacc = reinterpret_cast<float2*>(&ring[0][0]);   // ring no longer needed
    if (lane == 0) wacc[wave] = make_float2(s0, s1);
    __syncthreads();
    if (tid == 0) {
        float a0 = 0.f, a1 = 0.f;
        #pragma unroll
        for (int i = 0; i < 8; ++i) { a0 += wacc[i].x; a1 += wacc[i].y; }
        partials[blockIdx.x] = make_float2(a0, a1);
    }
}

// -------- Finalize: per-image ratio, mean over 64 images. One wave.
__global__ void finalize_kernel(const float2* __restrict__ partials,
                                float* __restrict__ out) {
    const int lane = threadIdx.x;   // 64 threads, one per image
    float s0 = 0.f, s1 = 0.f;
    #pragma unroll
    for (int j = 0; j < NSTRIP; ++j) {
        const float2 pp = partials[lane * NSTRIP + j];
        s0 += pp.x; s1 += pp.y;
    }
    float q = s1 / s0;
    q = wave_reduce(q);
    if (lane == 0) out[0] = q * (1.0f / (float)BATCH);
}

extern "C" void kernel_launch(void* const* d_in, const int* in_sizes, int n_in,
                              void* d_out, int out_size, void* d_ws, size_t ws_size,
                              hipStream_t stream) {
    const float* pred = (const float*)d_in[0];
    const float* mask = (const float*)d_in[1];
    float2* partials = (float2*)d_ws;   // 1024 * 8B

    hipLaunchKernelGGL(fused_kernel, dim3(BATCH * NSTRIP), dim3(512), 0, stream,
                       pred, mask, partials);
    hipLaunchKernelGGL(finalize_kernel, dim3(1), dim3(64), 0, stream,
                       partials, (float*)d_out);
}

// Round 5
// 68.970 us; speedup vs baseline: 1.6679x; 1.6679x over previous
//
#include <hip/hip_runtime.h>
#include <math.h>

#define BATCH 64
#define H 512
#define W 512
#define KRAD 15
#define STRIP 32               // output rows per block
#define NSTRIP (H / STRIP)     // 16 strips per image
#define RING 40                // LDS ring slots (bf16 hsum rows); live range = 39

__device__ __forceinline__ float wave_reduce(float v) {
    #pragma unroll
    for (int off = 32; off > 0; off >>= 1) v += __shfl_xor(v, off);
    return v;
}

// barrier that waits only LDS ops (keeps global loads in flight across it)
__device__ __forceinline__ void lds_barrier() {
    asm volatile("s_waitcnt lgkmcnt(0)" ::: "memory");
    __builtin_amdgcn_s_barrier();
    asm volatile("" ::: "memory");
}

// f32 -> bf16 bits (round-to-nearest-even)
__device__ __forceinline__ unsigned bf16b(float f) {
    unsigned u = __float_as_uint(f);
    return (u + 0x7FFFu + ((u >> 16) & 1u)) >> 16;
}
__device__ __forceinline__ float fbf16(unsigned short s) {
    return __uint_as_float(((unsigned)s) << 16);
}

__device__ __forceinline__ void load_row(const float* __restrict__ base, int r, int lane,
                                         float4& a, float4& b) {
    if (0 <= r && r < H) {
        const float4* p4 = reinterpret_cast<const float4*>(base + (size_t)r * W + lane * 8);
        a = p4[0]; b = p4[1];
    } else {
        a = make_float4(0.f, 0.f, 0.f, 0.f);
        b = a;
    }
}

// Wave-wide horizontal 31-box-sum of one row (from registers), bf16-pack to LDS.
__device__ __forceinline__ void scan_store(float4 va, float4 vb, int lane,
                                           unsigned short* dst) {
    float v[8] = {va.x, va.y, va.z, va.w, vb.x, vb.y, vb.z, vb.w};
    float P[8];
    float run = 0.f;
    #pragma unroll
    for (int k = 0; k < 8; ++k) { run += v[k]; P[k] = run; }
    float scan = run;
    #pragma unroll
    for (int off = 1; off < 64; off <<= 1) {
        float n = __shfl_up(scan, off);
        if (lane >= off) scan += n;
    }
    const float excl = scan - run;
    #pragma unroll
    for (int k = 0; k < 8; ++k) P[k] += excl;        // inclusive prefix at x=8*lane+k
    const float total = __shfl(P[7], 63);
    // out[x] = P[min(x+15,511)] - (x>=16 ? P[x-16] : 0)
    float shA[8], shB[8];
    shA[0] = __shfl_down(P[7], 1);
    #pragma unroll
    for (int k = 1; k < 8; ++k) shA[k] = __shfl_down(P[k - 1], 2);
    #pragma unroll
    for (int k = 0; k < 8; ++k) shB[k] = __shfl_up(P[k], 2);
    const int xb = lane * 8;
    float o[8];
    #pragma unroll
    for (int k = 0; k < 8; ++k) {
        const int x = xb + k;
        const float A  = (x + KRAD <= W - 1) ? shA[k] : total;
        const float Bv = (x >= KRAD + 1) ? shB[k] : 0.f;
        o[k] = A - Bv;
    }
    uint4 wv;
    wv.x = bf16b(o[0]) | (bf16b(o[1]) << 16);
    wv.y = bf16b(o[2]) | (bf16b(o[3]) << 16);
    wv.z = bf16b(o[4]) | (bf16b(o[5]) << 16);
    wv.w = bf16b(o[6]) | (bf16b(o[7]) << 16);
    *reinterpret_cast<uint4*>(dst + xb) = wv;        // 16B, conflict-free
}

// -------- Fused: horizontal scan -> 40-slot bf16 LDS ring -> vertical window + loss.
// slot(row) = (row - r0 + 16) mod 40; all indices compile-time via full unroll.
__global__ __launch_bounds__(512, 4) void fused_kernel(const float* __restrict__ pred,
                                                       const float* __restrict__ mask,
                                                       float2* __restrict__ partials) {
    __shared__ unsigned short ring[RING][W];         // 40960 B exactly

    const int tid  = threadIdx.x;
    const int wave = tid >> 6;
    const int lane = tid & 63;
    const int img   = blockIdx.x >> 4;               // NSTRIP = 16
    const int strip = blockIdx.x & 15;
    const int r0 = strip * STRIP;
    const int c  = tid;
    const float* mk = mask + (size_t)img * (H * W);
    const float* pr = pred + (size_t)img * (H * W);

    // Prologue: fill offsets 0..30 (rows r0-16 .. r0+14), pipelined 1-deep.
    {
        float4 pa, pb;
        int pidx = wave;
        load_row(mk, r0 - 16 + pidx, lane, pa, pb);
        #pragma unroll
        for (int gp = 0; gp < 4; ++gp) {
            float4 na, nb;
            const int nidx = pidx + 8;
            if (gp < 3 && nidx < 31) load_row(mk, r0 - 16 + nidx, lane, na, nb);
            if (pidx < 31) scan_store(pa, pb, lane, &ring[pidx][0]);
            pa = na; pb = nb; pidx = nidx;
        }
    }

    // Preload scan input for group 0 (rows r0+15+wave)
    float4 sva, svb;
    load_row(mk, r0 + 15 + wave, lane, sva, svb);

    lds_barrier();

    // Initial vertical sum: offsets 1..30 (rows r0-15 .. r0+14)
    float vsum = 0.f;
    #pragma unroll
    for (int s = 1; s <= 30; ++s) vsum += fbf16(ring[s][c]);

    float s0 = 0.f, s1 = 0.f;
    const float inv_k2 = 1.0f / 961.0f;

    #pragma unroll
    for (int g = 0; g < STRIP / 8; ++g) {
        // Phase A: store scan of row r0+8g+15+wave at offset 8g+31+wave
        {
            const int off = 8 * g + 31 + wave;
            const int slot = (off >= RING) ? off - RING : off;
            scan_store(sva, svb, lane, &ring[slot][0]);
        }
        // Prefetch next group's scan input; stays in flight across lds_barrier
        if (g + 1 < STRIP / 8) load_row(mk, r0 + 8 * (g + 1) + 15 + wave, lane, sva, svb);

        lds_barrier();

        // Phase B: batch LDS + global reads for 8 rows, then register chain
        float addv[8], subv[8], m[8], p[8];
        #pragma unroll
        for (int i = 0; i < 8; ++i) {
            const int offA = 8 * g + 31 + i;                 // compile-time
            const int slotA = (offA >= RING) ? offA - RING : offA;
            addv[i] = fbf16(ring[slotA][c]);
            subv[i] = fbf16(ring[8 * g + i][c]);             // never wraps
        }
        #pragma unroll
        for (int i = 0; i < 8; ++i) {
            const int y = r0 + 8 * g + i;
            m[i] = mk[(size_t)y * W + c];
            p[i] = pr[(size_t)y * W + c];
        }
        #pragma unroll
        for (int i = 0; i < 8; ++i) {
            vsum += addv[i] - subv[i];                       // window [y-15, y+15]
            const float avg = vsum * inv_k2;
            const float w = 1.0f + 5.0f * fabsf(avg - m[i]);
            const float e = __expf(-fabsf(p[i]));
            const float softplus = __logf(1.0f + e);         // log1p(e), e in (0,1]
            const float bce = fmaxf(p[i], 0.0f) - p[i] * m[i] + softplus;
            const float r1pe = __builtin_amdgcn_rcpf(1.0f + e);
            const float sig = (p[i] >= 0.0f) ? r1pe : e * r1pe;
            const float inter = sig * m[i];
            const float denom = sig + m[i] - inter + 1.0f;   // union - inter + 1
            const float iou = 1.0f - (inter + 1.0f) * __builtin_amdgcn_rcpf(denom);
            s0 += w;
            s1 += w * (bce + iou);
        }
        lds_barrier();   // ring slots free to overwrite next group
    }

    s0 = wave_reduce(s0);
    s1 = wave_reduce(s1);
    float2* wacc = reinterpret_cast<float2*>(&ring[0][0]);   // ring no longer needed
    if (lane == 0) wacc[wave] = make_float2(s0, s1);
    __syncthreads();
    if (tid == 0) {
        float a0 = 0.f, a1 = 0.f;
        #pragma unroll
        for (int i = 0; i < 8; ++i) { a0 += wacc[i].x; a1 += wacc[i].y; }
        partials[blockIdx.x] = make_float2(a0, a1);
    }
}

// -------- Finalize: per-image ratio, mean over 64 images. One wave.
__global__ void finalize_kernel(const float2* __restrict__ partials,
                                float* __restrict__ out) {
    const int lane = threadIdx.x;   // 64 threads, one per image
    float s0 = 0.f, s1 = 0.f;
    #pragma unroll
    for (int j = 0; j < NSTRIP; ++j) {
        const float2 pp = partials[lane * NSTRIP + j];
        s0 += pp.x; s1 += pp.y;
    }
    float q = s1 / s0;
    q = wave_reduce(q);
    if (lane == 0) out[0] = q * (1.0f / (float)BATCH);
}

extern "C" void kernel_launch(void* const* d_in, const int* in_sizes, int n_in,
                              void* d_out, int out_size, void* d_ws, size_t ws_size,
                              hipStream_t stream) {
    const float* pred = (const float*)d_in[0];
    const float* mask = (const float*)d_in[1];
    float2* partials = (float2*)d_ws;   // 1024 * 8B

    hipLaunchKernelGGL(fused_kernel, dim3(BATCH * NSTRIP), dim3(512), 0, stream,
                       pred, mask, partials);
    hipLaunchKernelGGL(finalize_kernel, dim3(1), dim3(64), 0, stream,
                       partials, (float*)d_out);
}

// Round 6
// 64.592 us; speedup vs baseline: 1.7810x; 1.0678x over previous
//
#include <hip/hip_runtime.h>
#include <math.h>

#define BATCH 64
#define H 512
#define W 512
#define KRAD 15
#define STRIP 32               // output rows per block
#define NSTRIP (H / STRIP)     // 16 strips per image
#define RING 40                // LDS ring slots (bf16 hsum rows); live range = 39

__device__ __forceinline__ float wave_reduce(float v) {
    #pragma unroll
    for (int off = 32; off > 0; off >>= 1) v += __shfl_xor(v, off);
    return v;
}

// f32 -> bf16 bits (round-to-nearest-even)
__device__ __forceinline__ unsigned bf16b(float f) {
    unsigned u = __float_as_uint(f);
    return (u + 0x7FFFu + ((u >> 16) & 1u)) >> 16;
}
__device__ __forceinline__ float fbf16(unsigned short s) {
    return __uint_as_float(((unsigned)s) << 16);
}

// One wave: load mask row r (zero-padded outside [0,H)), 31-wide horizontal
// box sum via register scan, bf16-pack into ring row dst.
__device__ __forceinline__ void scan_row(const float* __restrict__ img_base, int r,
                                         int lane, unsigned short* dst) {
    float o[8];
    if (0 <= r && r < H) {
        const float4* in4 = reinterpret_cast<const float4*>(img_base + (size_t)r * W + lane * 8);
        float4 va = in4[0], vb = in4[1];
        float v[8] = {va.x, va.y, va.z, va.w, vb.x, vb.y, vb.z, vb.w};
        float P[8];
        float run = 0.f;
        #pragma unroll
        for (int k = 0; k < 8; ++k) { run += v[k]; P[k] = run; }
        float scan = run;
        #pragma unroll
        for (int off = 1; off < 64; off <<= 1) {
            float n = __shfl_up(scan, off);
            if (lane >= off) scan += n;
        }
        const float excl = scan - run;
        #pragma unroll
        for (int k = 0; k < 8; ++k) P[k] += excl;        // inclusive prefix at x=8*lane+k
        const float total = __shfl(P[7], 63);
        // out[x] = P[min(x+15,511)] - (x>=16 ? P[x-16] : 0)
        float shA[8], shB[8];
        shA[0] = __shfl_down(P[7], 1);
        #pragma unroll
        for (int k = 1; k < 8; ++k) shA[k] = __shfl_down(P[k - 1], 2);
        #pragma unroll
        for (int k = 0; k < 8; ++k) shB[k] = __shfl_up(P[k], 2);
        const int xb = lane * 8;
        #pragma unroll
        for (int k = 0; k < 8; ++k) {
            const int x = xb + k;
            const float A  = (x + KRAD <= W - 1) ? shA[k] : total;
            const float Bv = (x >= KRAD + 1) ? shB[k] : 0.f;
            o[k] = A - Bv;
        }
    } else {
        #pragma unroll
        for (int k = 0; k < 8; ++k) o[k] = 0.f;
    }
    uint4 wv;
    wv.x = bf16b(o[0]) | (bf16b(o[1]) << 16);
    wv.y = bf16b(o[2]) | (bf16b(o[3]) << 16);
    wv.z = bf16b(o[4]) | (bf16b(o[5]) << 16);
    wv.w = bf16b(o[6]) | (bf16b(o[7]) << 16);
    *reinterpret_cast<uint4*>(dst + lane * 8) = wv;      // 16B, conflict-free
}

// -------- Fused: horizontal scan -> 40-slot bf16 LDS ring -> vertical window + loss.
// slot(row) = (row - r0 + 16) mod 40; all ring indices compile-time via full unroll.
__global__ __launch_bounds__(512) void fused_kernel(const float* __restrict__ pred,
                                                    const float* __restrict__ mask,
                                                    float2* __restrict__ partials) {
    __shared__ unsigned short ring[RING][W];             // 40960 B exactly

    const int tid  = threadIdx.x;
    const int wave = tid >> 6;
    const int lane = tid & 63;
    const int img   = blockIdx.x >> 4;                   // NSTRIP = 16
    const int strip = blockIdx.x & 15;
    const int r0 = strip * STRIP;
    const int c  = tid;
    const float* mk = mask + (size_t)img * (H * W);
    const float* pr = pred + (size_t)img * (H * W);

    // Prologue: fill offsets 0..30 (rows r0-16 .. r0+14)
    #pragma unroll
    for (int gp = 0; gp < 4; ++gp) {
        const int idx = gp * 8 + wave;
        if (idx < 31) scan_row(mk, r0 - 16 + idx, lane, &ring[idx][0]);
    }
    __syncthreads();

    // Initial vertical sum: offsets 1..30 (rows r0-15 .. r0+14)
    float vsum = 0.f;
    #pragma unroll
    for (int s = 1; s <= 30; ++s) vsum += fbf16(ring[s][c]);

    float s0 = 0.f, s1 = 0.f;
    const float inv_k2 = 1.0f / 961.0f;

    #pragma unroll
    for (int g = 0; g < STRIP / 8; ++g) {
        // Phase A: scan row r0+8g+15+wave into offset 8g+31+wave (mod 40)
        {
            const int off = 8 * g + 31 + wave;
            const int slot = (off >= RING) ? off - RING : off;
            scan_row(mk, r0 + 8 * g + 15 + wave, lane, &ring[slot][0]);
        }
        __syncthreads();

        // Phase B: batch LDS + global reads for 8 rows, then register chain
        float addv[8], subv[8], m[8], p[8];
        #pragma unroll
        for (int i = 0; i < 8; ++i) {
            const int offA = 8 * g + 31 + i;             // compile-time
            const int slotA = (offA >= RING) ? offA - RING : offA;
            addv[i] = fbf16(ring[slotA][c]);
            subv[i] = fbf16(ring[8 * g + i][c]);         // never wraps (max 31)
        }
        #pragma unroll
        for (int i = 0; i < 8; ++i) {
            const int y = r0 + 8 * g + i;
            m[i] = mk[(size_t)y * W + c];
            p[i] = pr[(size_t)y * W + c];
        }
        #pragma unroll
        for (int i = 0; i < 8; ++i) {
            vsum += addv[i] - subv[i];                   // window [y-15, y+15]
            const float avg = vsum * inv_k2;
            const float w = 1.0f + 5.0f * fabsf(avg - m[i]);
            const float e = __expf(-fabsf(p[i]));
            const float softplus = __logf(1.0f + e);     // log1p(e), e in (0,1]
            const float bce = fmaxf(p[i], 0.0f) - p[i] * m[i] + softplus;
            const float r1pe = __builtin_amdgcn_rcpf(1.0f + e);
            const float sig = (p[i] >= 0.0f) ? r1pe : e * r1pe;
            const float inter = sig * m[i];
            const float denom = sig + m[i] - inter + 1.0f;  // union - inter + 1
            const float iou = 1.0f - (inter + 1.0f) * __builtin_amdgcn_rcpf(denom);
            s0 += w;
            s1 += w * (bce + iou);
        }
        __syncthreads();   // ring slots free to overwrite next group
    }

    s0 = wave_reduce(s0);
    s1 = wave_reduce(s1);
    float2* wacc = reinterpret_cast<float2*>(&ring[0][0]);   // alias: ring dead now
    if (lane == 0) wacc[wave] = make_float2(s0, s1);
    __syncthreads();
    if (tid == 0) {
        float a0 = 0.f, a1 = 0.f;
        #pragma unroll
        for (int i = 0; i < 8; ++i) { a0 += wacc[i].x; a1 += wacc[i].y; }
        partials[blockIdx.x] = make_float2(a0, a1);
    }
}

// -------- Finalize: per-image ratio, mean over 64 images. One wave.
__global__ void finalize_kernel(const float2* __restrict__ partials,
                                float* __restrict__ out) {
    const int lane = threadIdx.x;   // 64 threads, one per image
    float s0 = 0.f, s1 = 0.f;
    #pragma unroll
    for (int j = 0; j < NSTRIP; ++j) {
        const float2 pp = partials[lane * NSTRIP + j];
        s0 += pp.x; s1 += pp.y;
    }
    float q = s1 / s0;
    q = wave_reduce(q);
    if (lane == 0) out[0] = q * (1.0f / (float)BATCH);
}

extern "C" void kernel_launch(void* const* d_in, const int* in_sizes, int n_in,
                              void* d_out, int out_size, void* d_ws, size_t ws_size,
                              hipStream_t stream) {
    const float* pred = (const float*)d_in[0];
    const float* mask = (const float*)d_in[1];
    float2* partials = (float2*)d_ws;   // 1024 * 8B

    hipLaunchKernelGGL(fused_kernel, dim3(BATCH * NSTRIP), dim3(512), 0, stream,
                       pred, mask, partials);
    hipLaunchKernelGGL(finalize_kernel, dim3(1), dim3(64), 0, stream,
                       partials, (float*)d_out);
}

// Round 7
// 50.336 us; speedup vs baseline: 2.2854x; 1.2832x over previous
//
#include <hip/hip_runtime.h>
#include <math.h>

#define BATCH 64
#define H 512
#define W 512
#define KRAD 15
#define STRIP 64               // output rows per block
#define NSTRIP (H / STRIP)     // 8 strips per image
#define RING 64                // LDS ring slots (bf16 hsum rows), &63 indexing

__device__ __forceinline__ float wave_reduce(float v) {
    #pragma unroll
    for (int off = 32; off > 0; off >>= 1) v += __shfl_xor(v, off);
    return v;
}

// barrier that waits only LDS ops (keeps global loads in flight across it)
__device__ __forceinline__ void lds_barrier() {
    asm volatile("s_waitcnt lgkmcnt(0)" ::: "memory");
    __builtin_amdgcn_s_barrier();
    asm volatile("" ::: "memory");
}

// f32 -> bf16 bits (round-to-nearest-even)
__device__ __forceinline__ unsigned bf16b(float f) {
    unsigned u = __float_as_uint(f);
    return (u + 0x7FFFu + ((u >> 16) & 1u)) >> 16;
}
__device__ __forceinline__ float fbf16(unsigned short s) {
    return __uint_as_float(((unsigned)s) << 16);
}

__device__ __forceinline__ void load_row(const float* __restrict__ base, int r, int lane,
                                         float4& a, float4& b) {
    if (0 <= r && r < H) {
        const float4* p4 = reinterpret_cast<const float4*>(base + (size_t)r * W + lane * 8);
        a = p4[0]; b = p4[1];
    } else {
        a = make_float4(0.f, 0.f, 0.f, 0.f);
        b = a;
    }
}

// Wave-wide horizontal 31-box-sum of one row (from registers), bf16-pack to LDS.
__device__ __forceinline__ void scan_store(float4 va, float4 vb, int lane,
                                           unsigned short* dst) {
    float v[8] = {va.x, va.y, va.z, va.w, vb.x, vb.y, vb.z, vb.w};
    float P[8];
    float run = 0.f;
    #pragma unroll
    for (int k = 0; k < 8; ++k) { run += v[k]; P[k] = run; }
    float scan = run;
    #pragma unroll
    for (int off = 1; off < 64; off <<= 1) {
        float n = __shfl_up(scan, off);
        if (lane >= off) scan += n;
    }
    const float excl = scan - run;
    #pragma unroll
    for (int k = 0; k < 8; ++k) P[k] += excl;        // inclusive prefix at x=8*lane+k
    const float total = __shfl(P[7], 63);
    // out[x] = P[min(x+15,511)] - (x>=16 ? P[x-16] : 0)
    float shA[8], shB[8];
    shA[0] = __shfl_down(P[7], 1);
    #pragma unroll
    for (int k = 1; k < 8; ++k) shA[k] = __shfl_down(P[k - 1], 2);
    #pragma unroll
    for (int k = 0; k < 8; ++k) shB[k] = __shfl_up(P[k], 2);
    const int xb = lane * 8;
    float o[8];
    #pragma unroll
    for (int k = 0; k < 8; ++k) {
        const int x = xb + k;
        const float A  = (x + KRAD <= W - 1) ? shA[k] : total;
        const float Bv = (x >= KRAD + 1) ? shB[k] : 0.f;
        o[k] = A - Bv;
    }
    uint4 wv;
    wv.x = bf16b(o[0]) | (bf16b(o[1]) << 16);
    wv.y = bf16b(o[2]) | (bf16b(o[3]) << 16);
    wv.z = bf16b(o[4]) | (bf16b(o[5]) << 16);
    wv.w = bf16b(o[6]) | (bf16b(o[7]) << 16);
    *reinterpret_cast<uint4*>(dst + xb) = wv;        // 16B, conflict-free
}

// -------- Fused: horizontal scan -> bf16 LDS ring -> vertical window + loss.
// One barrier per 8-row group (RING=64 slack makes the tail barrier unnecessary:
// group g+1/g+2 writes land at offsets 8g+39..54, mod-64 disjoint from group g's
// read slots 8g..8g+7 and 8g+31..8g+38; max skew across one barrier is 2 groups).
__global__ __launch_bounds__(512) void fused_kernel(const float* __restrict__ pred,
                                                    const float* __restrict__ mask,
                                                    float2* __restrict__ partials) {
    __shared__ unsigned short ring[RING][W];         // 64 KB

    const int tid  = threadIdx.x;
    const int wave = tid >> 6;
    const int lane = tid & 63;
    const int img   = blockIdx.x >> 3;               // NSTRIP = 8
    const int strip = blockIdx.x & 7;
    const int r0 = strip * STRIP;
    const int c  = tid;
    const float* mk = mask + (size_t)img * (H * W);
    const float* pr = pred + (size_t)img * (H * W);

    // Prologue: fill slots 0..30 (rows r0-16 .. r0+14)
    #pragma unroll
    for (int gp = 0; gp < 4; ++gp) {
        const int idx = gp * 8 + wave;
        if (idx < 31) {
            float4 la, lb;
            load_row(mk, r0 - 16 + idx, lane, la, lb);
            scan_store(la, lb, lane, &ring[idx][0]);
        }
    }

    // Issue group-0 prefetches before the barrier: scan input + m/p rows.
    float4 sva, svb;
    load_row(mk, r0 + 15 + wave, lane, sva, svb);
    float m[8], p[8];
    #pragma unroll
    for (int i = 0; i < 8; ++i) {
        m[i] = mk[(size_t)(r0 + i) * W + c];
        p[i] = pr[(size_t)(r0 + i) * W + c];
    }

    lds_barrier();

    // Initial vertical sum: slots 1..30 (rows r0-15 .. r0+14)
    float vsum = 0.f;
    #pragma unroll
    for (int s = 1; s <= 30; ++s) vsum += fbf16(ring[s][c]);

    float s0 = 0.f, s1 = 0.f;
    const float inv_k2 = 1.0f / 961.0f;

    for (int g = 0; g < STRIP / 8; ++g) {
        const int ybase = r0 + 8 * g;
        // Phase A: scan row ybase+15+wave into slot (8g+31+wave) & 63
        scan_store(sva, svb, lane, &ring[(8 * g + 31 + wave) & (RING - 1)][0]);
        // Re-issue scan-input prefetch for next group (in flight across barrier)
        if (g + 1 < STRIP / 8) load_row(mk, ybase + 8 + 15 + wave, lane, sva, svb);

        lds_barrier();

        // Phase B: LDS window reads; m/p already prefetched last group.
        float addv[8], subv[8];
        #pragma unroll
        for (int i = 0; i < 8; ++i) {
            addv[i] = fbf16(ring[(8 * g + 31 + i) & (RING - 1)][c]);
            subv[i] = fbf16(ring[(8 * g + i) & (RING - 1)][c]);
        }
        #pragma unroll
        for (int i = 0; i < 8; ++i) {
            vsum += addv[i] - subv[i];                   // window [y-15, y+15]
            const float avg = vsum * inv_k2;
            const float w = 1.0f + 5.0f * fabsf(avg - m[i]);
            const float e = __expf(-fabsf(p[i]));
            const float softplus = __logf(1.0f + e);     // log1p(e), e in (0,1]
            const float bce = fmaxf(p[i], 0.0f) - p[i] * m[i] + softplus;
            const float r1pe = __builtin_amdgcn_rcpf(1.0f + e);
            const float sig = (p[i] >= 0.0f) ? r1pe : e * r1pe;
            const float inter = sig * m[i];
            const float denom = sig + m[i] - inter + 1.0f;  // union - inter + 1
            const float iou = 1.0f - (inter + 1.0f) * __builtin_amdgcn_rcpf(denom);
            s0 += w;
            s1 += w * (bce + iou);
        }
        // Prefetch next group's m/p after last use of current (single buffer;
        // stays in flight across next barrier + phase A).
        if (g + 1 < STRIP / 8) {
            #pragma unroll
            for (int i = 0; i < 8; ++i) {
                m[i] = mk[(size_t)(ybase + 8 + i) * W + c];
                p[i] = pr[(size_t)(ybase + 8 + i) * W + c];
            }
        }
        // NO tail barrier: ring slack covers 2-group skew (see header comment).
    }

    s0 = wave_reduce(s0);
    s1 = wave_reduce(s1);
    __syncthreads();                                     // all ring reads done
    float2* wacc = reinterpret_cast<float2*>(&ring[0][0]);
    if (lane == 0) wacc[wave] = make_float2(s0, s1);
    __syncthreads();
    if (tid == 0) {
        float a0 = 0.f, a1 = 0.f;
        #pragma unroll
        for (int i = 0; i < 8; ++i) { a0 += wacc[i].x; a1 += wacc[i].y; }
        partials[blockIdx.x] = make_float2(a0, a1);
    }
}

// -------- Finalize: per-image ratio, mean over 64 images. One wave.
__global__ void finalize_kernel(const float2* __restrict__ partials,
                                float* __restrict__ out) {
    const int lane = threadIdx.x;   // 64 threads, one per image
    float s0 = 0.f, s1 = 0.f;
    #pragma unroll
    for (int j = 0; j < NSTRIP; ++j) {
        const float2 pp = partials[lane * NSTRIP + j];
        s0 += pp.x; s1 += pp.y;
    }
    float q = s1 / s0;
    q = wave_reduce(q);
    if (lane == 0) out[0] = q * (1.0f / (float)BATCH);
}

extern "C" void kernel_launch(void* const* d_in, const int* in_sizes, int n_in,
                              void* d_out, int out_size, void* d_ws, size_t ws_size,
                              hipStream_t stream) {
    const float* pred = (const float*)d_in[0];
    const float* mask = (const float*)d_in[1];
    float2* partials = (float2*)d_ws;   // 512 * 8B

    hipLaunchKernelGGL(fused_kernel, dim3(BATCH * NSTRIP), dim3(512), 0, stream,
                       pred, mask, partials);
    hipLaunchKernelGGL(finalize_kernel, dim3(1), dim3(64), 0, stream,
                       partials, (float*)d_out);
}

// Round 8
// 45.624 us; speedup vs baseline: 2.5214x; 1.1033x over previous
//
#include <hip/hip_runtime.h>
#include <math.h>

#define BATCH 64
#define H 512
#define W 512
#define KRAD 15
#define STRIP 64               // output rows per block
#define NSTRIP (H / STRIP)     // 8 strips per image
#define RING 40                // LDS ring slots (bf16 hsum rows); live range = 39

__device__ __forceinline__ float wave_reduce(float v) {
    #pragma unroll
    for (int off = 32; off > 0; off >>= 1) v += __shfl_xor(v, off);
    return v;
}

// f32 -> bf16 bits (round-to-nearest-even)
__device__ __forceinline__ unsigned bf16b(float f) {
    unsigned u = __float_as_uint(f);
    return (u + 0x7FFFu + ((u >> 16) & 1u)) >> 16;
}
__device__ __forceinline__ float fbf16(unsigned short s) {
    return __uint_as_float(((unsigned)s) << 16);
}

// One wave: load mask row r (zero-padded outside [0,H)), 31-wide horizontal
// box sum via register scan, bf16-pack into ring row dst.
__device__ __forceinline__ void scan_row(const float* __restrict__ img_base, int r,
                                         int lane, unsigned short* dst) {
    float o[8];
    if (0 <= r && r < H) {
        const float4* in4 = reinterpret_cast<const float4*>(img_base + (size_t)r * W + lane * 8);
        float4 va = in4[0], vb = in4[1];
        float v[8] = {va.x, va.y, va.z, va.w, vb.x, vb.y, vb.z, vb.w};
        float P[8];
        float run = 0.f;
        #pragma unroll
        for (int k = 0; k < 8; ++k) { run += v[k]; P[k] = run; }
        float scan = run;
        #pragma unroll
        for (int off = 1; off < 64; off <<= 1) {
            float n = __shfl_up(scan, off);
            if (lane >= off) scan += n;
        }
        const float excl = scan - run;
        #pragma unroll
        for (int k = 0; k < 8; ++k) P[k] += excl;        // inclusive prefix at x=8*lane+k
        const float total = __shfl(P[7], 63);
        // out[x] = P[min(x+15,511)] - (x>=16 ? P[x-16] : 0)
        float shA[8], shB[8];
        shA[0] = __shfl_down(P[7], 1);
        #pragma unroll
        for (int k = 1; k < 8; ++k) shA[k] = __shfl_down(P[k - 1], 2);
        #pragma unroll
        for (int k = 0; k < 8; ++k) shB[k] = __shfl_up(P[k], 2);
        const int xb = lane * 8;
        #pragma unroll
        for (int k = 0; k < 8; ++k) {
            const int x = xb + k;
            const float A  = (x + KRAD <= W - 1) ? shA[k] : total;
            const float Bv = (x >= KRAD + 1) ? shB[k] : 0.f;
            o[k] = A - Bv;
        }
    } else {
        #pragma unroll
        for (int k = 0; k < 8; ++k) o[k] = 0.f;
    }
    uint4 wv;
    wv.x = bf16b(o[0]) | (bf16b(o[1]) << 16);
    wv.y = bf16b(o[2]) | (bf16b(o[3]) << 16);
    wv.z = bf16b(o[4]) | (bf16b(o[5]) << 16);
    wv.w = bf16b(o[6]) | (bf16b(o[7]) << 16);
    *reinterpret_cast<uint4*>(dst + lane * 8) = wv;      // 16B, conflict-free
}

// -------- Fused: horizontal scan -> 40-slot bf16 LDS ring -> vertical window + loss.
// slot(offset) = offset mod 40, tracked incrementally:
//   sA = (8g+31) % 40  (phase-A store base / addv base), sA+k <= 46 -> one cond-sub
//   sB =  8g     % 40  (subv base), sB in {0,8,16,24,32}, sB+i <= 39 -> no wrap
__global__ __launch_bounds__(512) void fused_kernel(const float* __restrict__ pred,
                                                    const float* __restrict__ mask,
                                                    float2* __restrict__ partials) {
    __shared__ unsigned short ring[RING][W];             // 40960 B exactly

    const int tid  = threadIdx.x;
    const int wave = tid >> 6;
    const int lane = tid & 63;
    const int img   = blockIdx.x >> 3;                   // NSTRIP = 8
    const int strip = blockIdx.x & 7;
    const int r0 = strip * STRIP;
    const int c  = tid;
    const float* mk = mask + (size_t)img * (H * W);
    const float* pr = pred + (size_t)img * (H * W);

    // Prologue: fill slots 0..30 (rows r0-16 .. r0+14)
    #pragma unroll
    for (int gp = 0; gp < 4; ++gp) {
        const int idx = gp * 8 + wave;
        if (idx < 31) scan_row(mk, r0 - 16 + idx, lane, &ring[idx][0]);
    }
    __syncthreads();

    // Initial vertical sum: slots 1..30 (rows r0-15 .. r0+14)
    float vsum = 0.f;
    #pragma unroll
    for (int s = 1; s <= 30; ++s) vsum += fbf16(ring[s][c]);

    float s0 = 0.f, s1 = 0.f;
    const float inv_k2 = 1.0f / 961.0f;
    int sA = 31;   // (8g+31) % 40
    int sB = 0;    //  8g     % 40

    for (int g = 0; g < STRIP / 8; ++g) {
        const int ybase = r0 + 8 * g;
        // Phase A: scan row ybase+15+wave into slot (sA+wave) mod 40
        {
            int slot = sA + wave;
            if (slot >= RING) slot -= RING;
            scan_row(mk, ybase + 15 + wave, lane, &ring[slot][0]);
        }
        __syncthreads();

        // Phase B: batch LDS + global reads for 8 rows, then register chain
        float addv[8], subv[8], m[8], p[8];
        #pragma unroll
        for (int i = 0; i < 8; ++i) {
            int slotA = sA + i;
            if (slotA >= RING) slotA -= RING;
            addv[i] = fbf16(ring[slotA][c]);
            subv[i] = fbf16(ring[sB + i][c]);            // sB+i <= 39, never wraps
        }
        #pragma unroll
        for (int i = 0; i < 8; ++i) {
            const int y = ybase + i;
            m[i] = mk[(size_t)y * W + c];
            p[i] = pr[(size_t)y * W + c];
        }
        #pragma unroll
        for (int i = 0; i < 8; ++i) {
            vsum += addv[i] - subv[i];                   // window [y-15, y+15]
            const float avg = vsum * inv_k2;
            const float w = 1.0f + 5.0f * fabsf(avg - m[i]);
            const float e = __expf(-fabsf(p[i]));
            const float softplus = __logf(1.0f + e);     // log1p(e), e in (0,1]
            const float bce = fmaxf(p[i], 0.0f) - p[i] * m[i] + softplus;
            const float r1pe = __builtin_amdgcn_rcpf(1.0f + e);
            const float sig = (p[i] >= 0.0f) ? r1pe : e * r1pe;
            const float inter = sig * m[i];
            const float denom = sig + m[i] - inter + 1.0f;  // union - inter + 1
            const float iou = 1.0f - (inter + 1.0f) * __builtin_amdgcn_rcpf(denom);
            s0 += w;
            s1 += w * (bce + iou);
        }
        sA += 8; if (sA >= RING) sA -= RING;
        sB += 8; if (sB >= RING) sB -= RING;
        __syncthreads();   // ring slots free to overwrite next group
    }

    s0 = wave_reduce(s0);
    s1 = wave_reduce(s1);
    float2* wacc = reinterpret_cast<float2*>(&ring[0][0]);   // alias: ring dead now
    if (lane == 0) wacc[wave] = make_float2(s0, s1);
    __syncthreads();
    if (tid == 0) {
        float a0 = 0.f, a1 = 0.f;
        #pragma unroll
        for (int i = 0; i < 8; ++i) { a0 += wacc[i].x; a1 += wacc[i].y; }
        partials[blockIdx.x] = make_float2(a0, a1);
    }
}

// -------- Finalize: per-image ratio, mean over 64 images. One wave.
__global__ void finalize_kernel(const float2* __restrict__ partials,
                                float* __restrict__ out) {
    const int lane = threadIdx.x;   // 64 threads, one per image
    float s0 = 0.f, s1 = 0.f;
    #pragma unroll
    for (int j = 0; j < NSTRIP; ++j) {
        const float2 pp = partials[lane * NSTRIP + j];
        s0 += pp.x; s1 += pp.y;
    }
    float q = s1 / s0;
    q = wave_reduce(q);
    if (lane == 0) out[0] = q * (1.0f / (float)BATCH);
}

extern "C" void kernel_launch(void* const* d_in, const int* in_sizes, int n_in,
                              void* d_out, int out_size, void* d_ws, size_t ws_size,
                              hipStream_t stream) {
    const float* pred = (const float*)d_in[0];
    const float* mask = (const float*)d_in[1];
    float2* partials = (float2*)d_ws;   // 512 * 8B

    hipLaunchKernelGGL(fused_kernel, dim3(BATCH * NSTRIP), dim3(512), 0, stream,
                       pred, mask, partials);
    hipLaunchKernelGGL(finalize_kernel, dim3(1), dim3(64), 0, stream,
                       partials, (float*)d_out);
}